// Round 3
// baseline (1472.441 us; speedup 1.0000x reference)
//
#include <hip/hip_runtime.h>

#define NN 50000     // nodes
#define NE 800000    // edges per metapath
#define NP 4         // metapaths
#define DIN 256      // in_size
#define DD 256       // out dim
#define NH 128       // semantic attention hidden
#define SA 40        // LDS row stride in bf16 elems (80 B)
#define HCH 7168     // histogram chunk (7 chunks cover 50176 >= NN)
#define FCH 2048     // fill chunk (25 chunks cover 51200 >= NN)
#define NFC 25

typedef __attribute__((ext_vector_type(8))) short bf16x8;
typedef __attribute__((ext_vector_type(4))) float f32x4;

__device__ __forceinline__ unsigned short f2bf(float f) {
  unsigned u = __float_as_uint(f);
  u += 0x7fff + ((u >> 16) & 1);  // RNE
  return (unsigned short)(u >> 16);
}
__device__ __forceinline__ float bfl(unsigned u) { return __uint_as_float(u << 16); }
__device__ __forceinline__ float bfh(unsigned u) { return __uint_as_float(u & 0xffff0000u); }

// ---------------- histogram (atomic-free CSR build, stage 1) ----------------
// 56 blocks: (p, which in {src->rout, dst->deg_in+rin}, 7 key-chunks).
// Each block streams one 3.2 MB index array, counts its key range in LDS.

__global__ __launch_bounds__(256) void hist_kernel(
    const int* __restrict__ src, const int* __restrict__ dst,
    int* __restrict__ deg_in, float* __restrict__ rout, float* __restrict__ rin) {
  int b = blockIdx.x;            // 4 * 2 * 7
  int p = b / 14, r = b % 14;
  int which = r / 7, c = r % 7;
  int base = c * HCH;
  int nk = min(HCH, NN - base);
  __shared__ int hs[HCH];
  for (int k = threadIdx.x; k < HCH; k += 256) hs[k] = 0;
  __syncthreads();
  const int4* a4 = (const int4*)((which ? dst : src) + (size_t)p * NE);
  for (int i = threadIdx.x; i < NE / 4; i += 256) {
    int4 v = a4[i];
    int k;
    k = v.x - base; if ((unsigned)k < (unsigned)nk) atomicAdd(&hs[k], 1);
    k = v.y - base; if ((unsigned)k < (unsigned)nk) atomicAdd(&hs[k], 1);
    k = v.z - base; if ((unsigned)k < (unsigned)nk) atomicAdd(&hs[k], 1);
    k = v.w - base; if ((unsigned)k < (unsigned)nk) atomicAdd(&hs[k], 1);
  }
  __syncthreads();
  for (int k = threadIdx.x; k < nk; k += 256) {
    int d = hs[k];
    float rv = rsqrtf((float)max(d, 1));
    size_t idx = (size_t)p * NN + base + k;
    if (which) { deg_in[idx] = d; rin[idx] = rv; }
    else rout[idx] = rv;
  }
}

// ---------------- per-fill-chunk edge-count bases ----------------

__global__ __launch_bounds__(1024) void scan2_kernel(
    const int* __restrict__ deg_in, int* __restrict__ chunk_base,
    int* __restrict__ row_ptr) {
  __shared__ int csum[NP * NFC];
  int t = threadIdx.x, lane = t & 63, w = t >> 6;  // 16 waves
  for (int q = w; q < NP * NFC; q += 16) {
    int p = q / NFC, c = q % NFC;
    int base = c * FCH, nk = min(FCH, NN - base);
    int s = 0;
    for (int k = lane; k < nk; k += 64) s += deg_in[(size_t)p * NN + base + k];
#pragma unroll
    for (int o = 32; o > 0; o >>= 1) s += __shfl_down(s, o);
    if (lane == 0) csum[q] = s;
  }
  __syncthreads();
  if (t < NP) {
    int run = 0;
    for (int c = 0; c < NFC; ++c) { chunk_base[t * NFC + c] = run; run += csum[t * NFC + c]; }
    row_ptr[(size_t)t * (NN + 1) + NN] = NE;
  }
}

// ---------------- fill: local scan -> row_ptr + LDS cursors -> scatter col ------------

__global__ __launch_bounds__(256) void fill_kernel(
    const int* __restrict__ src, const int* __restrict__ dst,
    const int* __restrict__ deg_in, const int* __restrict__ chunk_base,
    int* __restrict__ row_ptr, int* __restrict__ col) {
  int b = blockIdx.x;  // 100
  int p = b / NFC, c = b % NFC;
  int base = c * FCH, nk = min(FCH, NN - base);
  __shared__ int cur[FCH];
  __shared__ int wsum[4];
  int t = threadIdx.x, lane = t & 63, w = t >> 6;
  const int* dg = deg_in + (size_t)p * NN + base;
  int loc[8];
  int s = 0;
#pragma unroll
  for (int j = 0; j < 8; ++j) {
    int k = t * 8 + j;
    int v = (k < nk) ? dg[k] : 0;
    loc[j] = s;
    s += v;
  }
  int incl = s;
#pragma unroll
  for (int o = 1; o < 64; o <<= 1) {
    int v = __shfl_up(incl, o);
    if (lane >= o) incl += v;
  }
  if (lane == 63) wsum[w] = incl;
  int wexcl = incl - s;
  __syncthreads();
  int wbase = 0;
  for (int k = 0; k < w; ++k) wbase += wsum[k];
  int tbase = chunk_base[b] + wbase + wexcl;
  int* rp = row_ptr + (size_t)p * (NN + 1) + base;
#pragma unroll
  for (int j = 0; j < 8; ++j) {
    int k = t * 8 + j;
    if (k < nk) {
      int pos = tbase + loc[j];
      rp[k] = pos;
      cur[k] = pos;
    }
  }
  __syncthreads();
  const int4* d4 = (const int4*)(dst + (size_t)p * NE);
  const int4* s4 = (const int4*)(src + (size_t)p * NE);
  int* colp = col + (size_t)p * NE;
  for (int i = t; i < NE / 4; i += 256) {
    int4 dv = d4[i];
    int4 sv = s4[i];
    int k;
    k = dv.x - base; if ((unsigned)k < (unsigned)nk) colp[atomicAdd(&cur[k], 1)] = sv.x;
    k = dv.y - base; if ((unsigned)k < (unsigned)nk) colp[atomicAdd(&cur[k], 1)] = sv.y;
    k = dv.z - base; if ((unsigned)k < (unsigned)nk) colp[atomicAdd(&cur[k], 1)] = sv.z;
    k = dv.w - base; if ((unsigned)k < (unsigned)nk) colp[atomicAdd(&cur[k], 1)] = sv.w;
  }
}

// ---------------- h -> bf16 ----------------

__global__ void cvt_h_kernel(const float4* __restrict__ h4, ushort4* __restrict__ h2) {
  int i = blockIdx.x * blockDim.x + threadIdx.x;
  if (i >= NN * DIN / 4) return;
  float4 v = h4[i];
  ushort4 o;
  o.x = f2bf(v.x); o.y = f2bf(v.y); o.z = f2bf(v.z); o.w = f2bf(v.w);
  h2[i] = o;
}

// ---------------- aggregation: g_p = rin * sum_src rout[src] * h2[src] (bf16 out) ----------

__global__ __launch_bounds__(256) void agg_kernel(
    const ushort* __restrict__ h2, const int* __restrict__ col,
    const int* __restrict__ row_ptr, const float* __restrict__ rout,
    const float* __restrict__ rin, ushort* __restrict__ g) {
  int p = blockIdx.y;
  int v = blockIdx.x * 4 + (threadIdx.x >> 6);
  int lane = threadIdx.x & 63;
  const int* colp = col + (size_t)p * NE;
  const float* rop = rout + (size_t)p * NN;
  int beg = row_ptr[p * (NN + 1) + v], end = row_ptr[p * (NN + 1) + v + 1];
  const uint2* hv = (const uint2*)h2;
  float a0 = 0, a1 = 0, a2 = 0, a3 = 0, b0 = 0, b1 = 0, b2 = 0, b3 = 0;
  int j = beg;
  for (; j + 1 < end; j += 2) {
    int s0 = colp[j], s1 = colp[j + 1];
    float r0 = rop[s0], r1 = rop[s1];
    uint2 u0 = hv[(size_t)s0 * 64 + lane];
    uint2 u1 = hv[(size_t)s1 * 64 + lane];
    a0 = fmaf(r0, bfl(u0.x), a0); a1 = fmaf(r0, bfh(u0.x), a1);
    a2 = fmaf(r0, bfl(u0.y), a2); a3 = fmaf(r0, bfh(u0.y), a3);
    b0 = fmaf(r1, bfl(u1.x), b0); b1 = fmaf(r1, bfh(u1.x), b1);
    b2 = fmaf(r1, bfl(u1.y), b2); b3 = fmaf(r1, bfh(u1.y), b3);
  }
  if (j < end) {
    int s0 = colp[j];
    float r0 = rop[s0];
    uint2 u0 = hv[(size_t)s0 * 64 + lane];
    a0 = fmaf(r0, bfl(u0.x), a0); a1 = fmaf(r0, bfh(u0.x), a1);
    a2 = fmaf(r0, bfl(u0.y), a2); a3 = fmaf(r0, bfh(u0.y), a3);
  }
  float ri = rin[(size_t)p * NN + v];
  ushort4 o;
  o.x = f2bf((a0 + b0) * ri); o.y = f2bf((a1 + b1) * ri);
  o.z = f2bf((a2 + b2) * ri); o.w = f2bf((a3 + b3) * ri);
  ((ushort4*)(g + ((size_t)p * NN + v) * DIN))[lane] = o;
}

// ---------------- Mt_p = (W_p @ W1)^T  (bf16, n-major), c_p = b_p @ W1 + b1 ----------------

__global__ void wmul_kernel(const float* __restrict__ Wgc, const float* __restrict__ W1,
                            ushort* __restrict__ Mt) {
  int p = blockIdx.y, k = blockIdx.x, j = threadIdx.x;  // block = 128
  const float* wrow = Wgc + ((size_t)p * DIN + k) * DD;
  float s = 0.f;
  for (int d = 0; d < DD; ++d) s = fmaf(wrow[d], W1[(size_t)d * NH + j], s);
  Mt[((size_t)p * NH + j) * DIN + k] = f2bf(s);
}

__global__ void cvec_kernel(const float* __restrict__ bgc, const float* __restrict__ W1,
                            const float* __restrict__ b1, float* __restrict__ cvec) {
  int p = blockIdx.x, j = threadIdx.x;  // block = 128
  const float* b = bgc + (size_t)p * DD;
  float s = b1[j];
  for (int d = 0; d < DD; ++d) s = fmaf(b[d], W1[(size_t)d * NH + j], s);
  cvec[p * NH + j] = s;
}

// ---------------- gemm_sem: ssum[p] = sum_{n,c} tanh(g_p @ M_p + c)[n,c] * w2[c] --------

__global__ __launch_bounds__(256) void gemm_sem(
    const ushort* __restrict__ g, const ushort* __restrict__ Mt,
    const float* __restrict__ cvec, const float* __restrict__ w2,
    float* __restrict__ ssum) {
  __shared__ ushort As[128 * SA];
  __shared__ ushort Bs[128 * SA];
  __shared__ float wsumf[4];
  const int tid = threadIdx.x;
  const int p = blockIdx.y;
  const int row0 = blockIdx.x * 128;
  const int wave = tid >> 6, lane = tid & 63;
  const int wr = wave >> 1, wc = wave & 1;
  const int srow = tid >> 2, sseg = tid & 3;
  const int fr = lane & 15, fk = (lane >> 4) * 8;
  const ushort* Ag = g + (size_t)p * NN * DIN;
  const ushort* Bg = Mt + (size_t)p * NH * DIN;
  int ar0 = row0 + srow; if (ar0 >= NN) ar0 = NN - 1;
  int ar1 = row0 + srow + 64; if (ar1 >= NN) ar1 = NN - 1;
  f32x4 acc[4][4] = {};
  for (int k2 = 0; k2 < DIN; k2 += 32) {
    uint4 av0 = *(const uint4*)(Ag + (size_t)ar0 * DIN + k2 + sseg * 8);
    uint4 av1 = *(const uint4*)(Ag + (size_t)ar1 * DIN + k2 + sseg * 8);
    uint4 bv0 = *(const uint4*)(Bg + (size_t)srow * DIN + k2 + sseg * 8);
    uint4 bv1 = *(const uint4*)(Bg + (size_t)(srow + 64) * DIN + k2 + sseg * 8);
    __syncthreads();
    *(uint4*)&As[srow * SA + sseg * 8] = av0;
    *(uint4*)&As[(srow + 64) * SA + sseg * 8] = av1;
    *(uint4*)&Bs[srow * SA + sseg * 8] = bv0;
    *(uint4*)&Bs[(srow + 64) * SA + sseg * 8] = bv1;
    __syncthreads();
    bf16x8 af[4], bfv[4];
#pragma unroll
    for (int t = 0; t < 4; ++t) {
      af[t] = *(const bf16x8*)&As[(wr * 64 + t * 16 + fr) * SA + fk];
      bfv[t] = *(const bf16x8*)&Bs[(wc * 64 + t * 16 + fr) * SA + fk];
    }
#pragma unroll
    for (int mt = 0; mt < 4; ++mt)
#pragma unroll
      for (int nt = 0; nt < 4; ++nt)
        acc[mt][nt] = __builtin_amdgcn_mfma_f32_16x16x32_bf16(af[mt], bfv[nt], acc[mt][nt], 0, 0, 0);
  }
  float s = 0.f;
#pragma unroll
  for (int nt = 0; nt < 4; ++nt) {
    int c = wc * 64 + nt * 16 + fr;
    float cc = cvec[p * NH + c];
    float ww = w2[c];
#pragma unroll
    for (int mt = 0; mt < 4; ++mt)
#pragma unroll
      for (int i = 0; i < 4; ++i) {
        int r = row0 + wr * 64 + mt * 16 + (lane >> 4) * 4 + i;
        if (r < NN) {
          float x = acc[mt][nt][i] + cc;
          x = fminf(fmaxf(x, -15.f), 15.f);
          float e = __expf(2.f * x);
          s = fmaf((e - 1.f) / (e + 1.f), ww, s);
        }
      }
  }
#pragma unroll
  for (int o = 32; o > 0; o >>= 1) s += __shfl_down(s, o);
  if (lane == 0) wsumf[wave] = s;
  __syncthreads();
  if (tid == 0) atomicAdd(&ssum[p], wsumf[0] + wsumf[1] + wsumf[2] + wsumf[3]);
}

// ---------------- beta + bout + beta-scaled W^T (bf16) ----------------

__global__ void beta_kernel(const float* __restrict__ ssum, const float* __restrict__ bgc,
                            float* __restrict__ beta, float* __restrict__ bout) {
  __shared__ float sb[NP];
  if (threadIdx.x == 0) {
    float m[NP];
    float mx = -1e30f;
    for (int p = 0; p < NP; ++p) {
      m[p] = ssum[p] / (float)NN;
      mx = fmaxf(mx, m[p]);
    }
    float tot = 0.f;
    for (int p = 0; p < NP; ++p) { m[p] = expf(m[p] - mx); tot += m[p]; }
    for (int p = 0; p < NP; ++p) { sb[p] = m[p] / tot; beta[p] = sb[p]; }
  }
  __syncthreads();
  int d = threadIdx.x;  // block = 256
  float s = 0.f;
  for (int p = 0; p < NP; ++p) s = fmaf(sb[p], bgc[p * DD + d], s);
  bout[d] = s;
}

__global__ void scaleWt_kernel(const float* __restrict__ Wgc, const float* __restrict__ beta,
                               ushort* __restrict__ Wt) {
  int i = blockIdx.x * blockDim.x + threadIdx.x;  // over DD * NP * DIN
  if (i >= DD * NP * DIN) return;
  int n = i >> 10;
  int pk = i & 1023;
  int p = pk >> 8, k = pk & 255;
  Wt[i] = f2bf(beta[p] * Wgc[((size_t)p * DIN + k) * DD + n]);
}

// ---------------- gemm_main: out = [g_0|..|g_3] @ Wt^T + bout ----------------

__global__ __launch_bounds__(256) void gemm_main(
    const ushort* __restrict__ g, const ushort* __restrict__ Wt,
    const float* __restrict__ bout, float* __restrict__ out) {
  __shared__ ushort As[128 * SA];
  __shared__ ushort Bs[128 * SA];
  const int tid = threadIdx.x;
  const int row0 = blockIdx.x * 128;
  const int col0 = blockIdx.y * 128;
  const int wave = tid >> 6, lane = tid & 63;
  const int wr = wave >> 1, wc = wave & 1;
  const int srow = tid >> 2, sseg = tid & 3;
  const int fr = lane & 15, fk = (lane >> 4) * 8;
  int ar0 = row0 + srow; if (ar0 >= NN) ar0 = NN - 1;
  int ar1 = row0 + srow + 64; if (ar1 >= NN) ar1 = NN - 1;
  f32x4 acc[4][4] = {};
  for (int p = 0; p < NP; ++p) {
    const ushort* Ag = g + (size_t)p * NN * DIN;
    for (int k2 = 0; k2 < DIN; k2 += 32) {
      uint4 av0 = *(const uint4*)(Ag + (size_t)ar0 * DIN + k2 + sseg * 8);
      uint4 av1 = *(const uint4*)(Ag + (size_t)ar1 * DIN + k2 + sseg * 8);
      uint4 bv0 = *(const uint4*)(Wt + (size_t)(col0 + srow) * (NP * DIN) + p * DIN + k2 + sseg * 8);
      uint4 bv1 = *(const uint4*)(Wt + (size_t)(col0 + srow + 64) * (NP * DIN) + p * DIN + k2 + sseg * 8);
      __syncthreads();
      *(uint4*)&As[srow * SA + sseg * 8] = av0;
      *(uint4*)&As[(srow + 64) * SA + sseg * 8] = av1;
      *(uint4*)&Bs[srow * SA + sseg * 8] = bv0;
      *(uint4*)&Bs[(srow + 64) * SA + sseg * 8] = bv1;
      __syncthreads();
      bf16x8 af[4], bfv[4];
#pragma unroll
      for (int t = 0; t < 4; ++t) {
        af[t] = *(const bf16x8*)&As[(wr * 64 + t * 16 + fr) * SA + fk];
        bfv[t] = *(const bf16x8*)&Bs[(wc * 64 + t * 16 + fr) * SA + fk];
      }
#pragma unroll
      for (int mt = 0; mt < 4; ++mt)
#pragma unroll
        for (int nt = 0; nt < 4; ++nt)
          acc[mt][nt] = __builtin_amdgcn_mfma_f32_16x16x32_bf16(af[mt], bfv[nt], acc[mt][nt], 0, 0, 0);
    }
  }
#pragma unroll
  for (int nt = 0; nt < 4; ++nt) {
    int c = col0 + wc * 64 + nt * 16 + fr;
    float bb = bout[c];
#pragma unroll
    for (int mt = 0; mt < 4; ++mt)
#pragma unroll
      for (int i = 0; i < 4; ++i) {
        int r = row0 + wr * 64 + mt * 16 + (lane >> 4) * 4 + i;
        if (r < NN) out[(size_t)r * DD + c] = acc[mt][nt][i] + bb;
      }
  }
}

// ---------------- launcher ----------------

extern "C" void kernel_launch(void* const* d_in, const int* in_sizes, int n_in,
                              void* d_out, int out_size, void* d_ws, size_t ws_size,
                              hipStream_t stream) {
  const float* h = (const float*)d_in[0];
  const int* src = (const int*)d_in[1];
  const int* dst = (const int*)d_in[2];
  const float* Wgc = (const float*)d_in[3];
  const float* bgc = (const float*)d_in[4];
  const float* W1 = (const float*)d_in[5];
  const float* b1 = (const float*)d_in[6];
  const float* w2 = (const float*)d_in[7];
  float* out = (float*)d_out;

  char* base = (char*)d_ws;
  size_t off = 0;
  auto alloc = [&](size_t bytes) -> char* {
    char* ptr = base + off;
    off = (off + bytes + 255) & ~(size_t)255;
    return ptr;
  };
  int* deg_in_i = (int*)alloc((size_t)NP * NN * sizeof(int));
  float* rout = (float*)alloc((size_t)NP * NN * sizeof(float));
  float* rin = (float*)alloc((size_t)NP * NN * sizeof(float));
  int* row_ptr = (int*)alloc((size_t)NP * (NN + 1) * sizeof(int));
  int* chunk_base = (int*)alloc((size_t)NP * NFC * sizeof(int));
  int* colbuf = (int*)alloc((size_t)NP * NE * sizeof(int));
  ushort* h2 = (ushort*)alloc((size_t)NN * DIN * sizeof(ushort));
  ushort* g = (ushort*)alloc((size_t)NP * NN * DIN * sizeof(ushort));
  ushort* Mt = (ushort*)alloc((size_t)NP * NH * DIN * sizeof(ushort));
  ushort* Wt = (ushort*)alloc((size_t)DD * NP * DIN * sizeof(ushort));
  float* cvec = (float*)alloc((size_t)NP * NH * sizeof(float));
  float* ssum = (float*)alloc(NP * sizeof(float));
  float* beta = (float*)alloc(NP * sizeof(float));
  float* bout = (float*)alloc(DD * sizeof(float));
  if (off > ws_size) return;

  hipMemsetAsync(ssum, 0, NP * sizeof(float), stream);

  hist_kernel<<<NP * 2 * 7, 256, 0, stream>>>(src, dst, deg_in_i, rout, rin);
  scan2_kernel<<<1, 1024, 0, stream>>>(deg_in_i, chunk_base, row_ptr);
  fill_kernel<<<NP * NFC, 256, 0, stream>>>(src, dst, deg_in_i, chunk_base, row_ptr, colbuf);
  cvt_h_kernel<<<(NN * DIN / 4 + 255) / 256, 256, 0, stream>>>((const float4*)h, (ushort4*)h2);
  agg_kernel<<<dim3(NN / 4, NP), 256, 0, stream>>>(h2, colbuf, row_ptr, rout, rin, g);
  wmul_kernel<<<dim3(DIN, NP), NH, 0, stream>>>(Wgc, W1, Mt);
  cvec_kernel<<<NP, NH, 0, stream>>>(bgc, W1, b1, cvec);
  gemm_sem<<<dim3((NN + 127) / 128, NP), 256, 0, stream>>>(g, Mt, cvec, w2, ssum);
  beta_kernel<<<1, 256, 0, stream>>>(ssum, bgc, beta, bout);
  scaleWt_kernel<<<(DD * NP * DIN + 255) / 256, 256, 0, stream>>>(Wgc, beta, Wt);
  gemm_main<<<dim3((NN + 127) / 128, 2), 256, 0, stream>>>(g, Wt, bout, out);
}

// Round 4
// 656.892 us; speedup vs baseline: 2.2415x; 2.2415x over previous
//
#include <hip/hip_runtime.h>

#define NN 50000     // nodes
#define NE 800000    // edges per metapath
#define NP 4         // metapaths
#define DIN 256      // in_size
#define DD 256       // out dim
#define NH 128       // semantic attention hidden
#define SA 40        // LDS row stride in bf16 elems (80 B)
#define NSEG 16      // edge segments
#define SEGE (NE / NSEG)   // 50000 edges per segment
#define FCH 8192     // key chunk (32 KB LDS cursors)
#define NFC 7        // 7 * 8192 = 57344 >= NN
#define SPAD(k) ((k) + ((k) >> 5))

typedef __attribute__((ext_vector_type(8))) short bf16x8;
typedef __attribute__((ext_vector_type(4))) float f32x4;

__device__ __forceinline__ unsigned short f2bf(float f) {
  unsigned u = __float_as_uint(f);
  u += 0x7fff + ((u >> 16) & 1);  // RNE
  return (unsigned short)(u >> 16);
}
__device__ __forceinline__ float bfl(unsigned u) { return __uint_as_float(u << 16); }
__device__ __forceinline__ float bfh(unsigned u) { return __uint_as_float(u & 0xffff0000u); }

// ---------------- CSR build stage 1: 2D histogram cnt[p][s][k] ----------------
// block (p, seg s, chunk c): stream 200 KB segment, count chunk keys in LDS.

__global__ __launch_bounds__(256) void hist2d_kernel(const int* __restrict__ idx,
                                                     int* __restrict__ cnt) {
  int bx = blockIdx.x;  // c + NFC*s
  int c = bx % NFC, s = bx / NFC;
  int p = blockIdx.y;
  int base = c * FCH, nk = min(FCH, NN - base);
  __shared__ int hs[FCH];
  for (int k = threadIdx.x; k < FCH; k += 256) hs[k] = 0;
  __syncthreads();
  const int4* a4 = (const int4*)(idx + (size_t)p * NE + (size_t)s * SEGE);
  for (int i = threadIdx.x; i < SEGE / 4; i += 256) {
    int4 v = a4[i];
    int k;
    k = v.x - base; if ((unsigned)k < (unsigned)nk) atomicAdd(&hs[k], 1);
    k = v.y - base; if ((unsigned)k < (unsigned)nk) atomicAdd(&hs[k], 1);
    k = v.z - base; if ((unsigned)k < (unsigned)nk) atomicAdd(&hs[k], 1);
    k = v.w - base; if ((unsigned)k < (unsigned)nk) atomicAdd(&hs[k], 1);
  }
  __syncthreads();
  int* out = cnt + (size_t)(p * NSEG + s) * NN + base;
  for (int k = threadIdx.x; k < nk; k += 256) out[k] = hs[k];
}

// ---------------- stage 2: per-key seg-prefix (in place), deg->rin/rout, local row_ptr ----

__global__ __launch_bounds__(1024) void scanA_kernel(
    int* __restrict__ cntD, const int* __restrict__ cntS,
    float* __restrict__ rin, float* __restrict__ rout,
    int* __restrict__ row_ptr, int* __restrict__ chunkdeg) {
  int c = blockIdx.x, p = blockIdx.y;
  int base = c * FCH, nk = min(FCH, NN - base);
  __shared__ int sdeg[FCH + (FCH >> 5)];
  __shared__ int wtot[16], wexc[16];
  int t = threadIdx.x;
  for (int kk = t; kk < FCH; kk += 1024) {
    int run = 0;
    if (kk < nk) {
      size_t o = (size_t)(p * NSEG) * NN + base + kk;
      for (int s = 0; s < NSEG; ++s) {
        size_t oo = o + (size_t)s * NN;
        int v = cntD[oo];
        cntD[oo] = run;
        run += v;
      }
      rin[(size_t)p * NN + base + kk] = rsqrtf((float)max(run, 1));
      int rs = 0;
      for (int s = 0; s < NSEG; ++s) rs += cntS[o + (size_t)s * NN];
      rout[(size_t)p * NN + base + kk] = rsqrtf((float)max(rs, 1));
    }
    sdeg[SPAD(kk)] = run;
  }
  __syncthreads();
  // block exclusive scan over FCH keys; thread t owns keys [t*8, t*8+8)
  int loc[8];
  int ssum = 0;
#pragma unroll
  for (int j = 0; j < 8; ++j) { loc[j] = ssum; ssum += sdeg[SPAD(t * 8 + j)]; }
  int incl = ssum;
  int lane = t & 63, w = t >> 6;
#pragma unroll
  for (int o = 1; o < 64; o <<= 1) {
    int v = __shfl_up(incl, o);
    if (lane >= o) incl += v;
  }
  if (lane == 63) wtot[w] = incl;
  __syncthreads();
  if (t == 0) {
    int r = 0;
    for (int i = 0; i < 16; ++i) { wexc[i] = r; r += wtot[i]; }
  }
  __syncthreads();
  int tbase = wexc[w] + incl - ssum;
  int* rp = row_ptr + (size_t)p * (NN + 1) + base;
#pragma unroll
  for (int j = 0; j < 8; ++j) {
    int k = t * 8 + j;
    if (k < nk) rp[k] = tbase + loc[j];
  }
  if (t == 1023) chunkdeg[p * NFC + c] = tbase + ssum;
}

// ---------------- stage 3: cross-chunk bases ----------------

__global__ void scanB_kernel(const int* __restrict__ chunkdeg, int* __restrict__ chunk_base,
                             int* __restrict__ row_ptr) {
  int t = threadIdx.x;
  if (t < NP) {
    int run = 0;
    for (int c = 0; c < NFC; ++c) { chunk_base[t * NFC + c] = run; run += chunkdeg[t * NFC + c]; }
    row_ptr[(size_t)t * (NN + 1) + NN] = NE;
  }
}

__global__ __launch_bounds__(1024) void rpfin_kernel(int* __restrict__ row_ptr,
                                                     const int* __restrict__ chunk_base) {
  int k = blockIdx.x * 1024 + threadIdx.x, p = blockIdx.y;
  if (k < NN) row_ptr[(size_t)p * (NN + 1) + k] += chunk_base[p * NFC + (k >> 13)];
}

// ---------------- stage 4: scatter col with LDS cursors ----------------

__global__ __launch_bounds__(256) void scatter_kernel(
    const int* __restrict__ src, const int* __restrict__ dst,
    const int* __restrict__ cntD, const int* __restrict__ row_ptr, int* __restrict__ col) {
  int bx = blockIdx.x;
  int c = bx % NFC, s = bx / NFC;
  int p = blockIdx.y;
  int base = c * FCH, nk = min(FCH, NN - base);
  __shared__ int cur[FCH];
  for (int k = threadIdx.x; k < nk; k += 256)
    cur[k] = row_ptr[(size_t)p * (NN + 1) + base + k] +
             cntD[(size_t)(p * NSEG + s) * NN + base + k];
  __syncthreads();
  const int4* d4 = (const int4*)(dst + (size_t)p * NE + (size_t)s * SEGE);
  const int4* s4 = (const int4*)(src + (size_t)p * NE + (size_t)s * SEGE);
  int* colp = col + (size_t)p * NE;
  for (int i = threadIdx.x; i < SEGE / 4; i += 256) {
    int4 dv = d4[i];
    int4 sv = s4[i];
    int k;
    k = dv.x - base; if ((unsigned)k < (unsigned)nk) colp[atomicAdd(&cur[k], 1)] = sv.x;
    k = dv.y - base; if ((unsigned)k < (unsigned)nk) colp[atomicAdd(&cur[k], 1)] = sv.y;
    k = dv.z - base; if ((unsigned)k < (unsigned)nk) colp[atomicAdd(&cur[k], 1)] = sv.z;
    k = dv.w - base; if ((unsigned)k < (unsigned)nk) colp[atomicAdd(&cur[k], 1)] = sv.w;
  }
}

// ---------------- h -> bf16 ----------------

__global__ void cvt_h_kernel(const float4* __restrict__ h4, ushort4* __restrict__ h2) {
  int i = blockIdx.x * blockDim.x + threadIdx.x;
  if (i >= NN * DIN / 4) return;
  float4 v = h4[i];
  ushort4 o;
  o.x = f2bf(v.x); o.y = f2bf(v.y); o.z = f2bf(v.z); o.w = f2bf(v.w);
  h2[i] = o;
}

// ---------------- aggregation: g_p = rin * sum_src rout[src] * h2[src] (bf16 out) ----------

__global__ __launch_bounds__(256) void agg_kernel(
    const ushort* __restrict__ h2, const int* __restrict__ col,
    const int* __restrict__ row_ptr, const float* __restrict__ rout,
    const float* __restrict__ rin, ushort* __restrict__ g) {
  int p = blockIdx.y;
  int v = blockIdx.x * 4 + (threadIdx.x >> 6);
  int lane = threadIdx.x & 63;
  const int* colp = col + (size_t)p * NE;
  const float* rop = rout + (size_t)p * NN;
  int beg = row_ptr[p * (NN + 1) + v], end = row_ptr[p * (NN + 1) + v + 1];
  const uint2* hv = (const uint2*)h2;
  float a0 = 0, a1 = 0, a2 = 0, a3 = 0, b0 = 0, b1 = 0, b2 = 0, b3 = 0;
  int j = beg;
  for (; j + 1 < end; j += 2) {
    int s0 = colp[j], s1 = colp[j + 1];
    float r0 = rop[s0], r1 = rop[s1];
    uint2 u0 = hv[(size_t)s0 * 64 + lane];
    uint2 u1 = hv[(size_t)s1 * 64 + lane];
    a0 = fmaf(r0, bfl(u0.x), a0); a1 = fmaf(r0, bfh(u0.x), a1);
    a2 = fmaf(r0, bfl(u0.y), a2); a3 = fmaf(r0, bfh(u0.y), a3);
    b0 = fmaf(r1, bfl(u1.x), b0); b1 = fmaf(r1, bfh(u1.x), b1);
    b2 = fmaf(r1, bfl(u1.y), b2); b3 = fmaf(r1, bfh(u1.y), b3);
  }
  if (j < end) {
    int s0 = colp[j];
    float r0 = rop[s0];
    uint2 u0 = hv[(size_t)s0 * 64 + lane];
    a0 = fmaf(r0, bfl(u0.x), a0); a1 = fmaf(r0, bfh(u0.x), a1);
    a2 = fmaf(r0, bfl(u0.y), a2); a3 = fmaf(r0, bfh(u0.y), a3);
  }
  float ri = rin[(size_t)p * NN + v];
  ushort4 o;
  o.x = f2bf((a0 + b0) * ri); o.y = f2bf((a1 + b1) * ri);
  o.z = f2bf((a2 + b2) * ri); o.w = f2bf((a3 + b3) * ri);
  ((ushort4*)(g + ((size_t)p * NN + v) * DIN))[lane] = o;
}

// ---------------- Mt_p = (W_p @ W1)^T  (bf16, n-major), c_p = b_p @ W1 + b1 ----------------

__global__ void wmul_kernel(const float* __restrict__ Wgc, const float* __restrict__ W1,
                            ushort* __restrict__ Mt) {
  int p = blockIdx.y, k = blockIdx.x, j = threadIdx.x;  // block = 128
  const float* wrow = Wgc + ((size_t)p * DIN + k) * DD;
  float s = 0.f;
  for (int d = 0; d < DD; ++d) s = fmaf(wrow[d], W1[(size_t)d * NH + j], s);
  Mt[((size_t)p * NH + j) * DIN + k] = f2bf(s);
}

__global__ void cvec_kernel(const float* __restrict__ bgc, const float* __restrict__ W1,
                            const float* __restrict__ b1, float* __restrict__ cvec) {
  int p = blockIdx.x, j = threadIdx.x;  // block = 128
  const float* b = bgc + (size_t)p * DD;
  float s = b1[j];
  for (int d = 0; d < DD; ++d) s = fmaf(b[d], W1[(size_t)d * NH + j], s);
  cvec[p * NH + j] = s;
}

// ---------------- gemm_sem: ssum[p] = sum_{n,c} tanh(g_p @ M_p + c)[n,c] * w2[c] --------

__global__ __launch_bounds__(256) void gemm_sem(
    const ushort* __restrict__ g, const ushort* __restrict__ Mt,
    const float* __restrict__ cvec, const float* __restrict__ w2,
    float* __restrict__ ssum) {
  __shared__ ushort As[128 * SA];
  __shared__ ushort Bs[128 * SA];
  __shared__ float wsumf[4];
  const int tid = threadIdx.x;
  const int p = blockIdx.y;
  const int row0 = blockIdx.x * 128;
  const int wave = tid >> 6, lane = tid & 63;
  const int wr = wave >> 1, wc = wave & 1;
  const int srow = tid >> 2, sseg = tid & 3;
  const int fr = lane & 15, fk = (lane >> 4) * 8;
  const ushort* Ag = g + (size_t)p * NN * DIN;
  const ushort* Bg = Mt + (size_t)p * NH * DIN;
  int ar0 = row0 + srow; if (ar0 >= NN) ar0 = NN - 1;
  int ar1 = row0 + srow + 64; if (ar1 >= NN) ar1 = NN - 1;
  f32x4 acc[4][4] = {};
  for (int k2 = 0; k2 < DIN; k2 += 32) {
    uint4 av0 = *(const uint4*)(Ag + (size_t)ar0 * DIN + k2 + sseg * 8);
    uint4 av1 = *(const uint4*)(Ag + (size_t)ar1 * DIN + k2 + sseg * 8);
    uint4 bv0 = *(const uint4*)(Bg + (size_t)srow * DIN + k2 + sseg * 8);
    uint4 bv1 = *(const uint4*)(Bg + (size_t)(srow + 64) * DIN + k2 + sseg * 8);
    __syncthreads();
    *(uint4*)&As[srow * SA + sseg * 8] = av0;
    *(uint4*)&As[(srow + 64) * SA + sseg * 8] = av1;
    *(uint4*)&Bs[srow * SA + sseg * 8] = bv0;
    *(uint4*)&Bs[(srow + 64) * SA + sseg * 8] = bv1;
    __syncthreads();
    bf16x8 af[4], bfv[4];
#pragma unroll
    for (int t = 0; t < 4; ++t) {
      af[t] = *(const bf16x8*)&As[(wr * 64 + t * 16 + fr) * SA + fk];
      bfv[t] = *(const bf16x8*)&Bs[(wc * 64 + t * 16 + fr) * SA + fk];
    }
#pragma unroll
    for (int mt = 0; mt < 4; ++mt)
#pragma unroll
      for (int nt = 0; nt < 4; ++nt)
        acc[mt][nt] = __builtin_amdgcn_mfma_f32_16x16x32_bf16(af[mt], bfv[nt], acc[mt][nt], 0, 0, 0);
  }
  float s = 0.f;
#pragma unroll
  for (int nt = 0; nt < 4; ++nt) {
    int c = wc * 64 + nt * 16 + fr;
    float cc = cvec[p * NH + c];
    float ww = w2[c];
#pragma unroll
    for (int mt = 0; mt < 4; ++mt)
#pragma unroll
      for (int i = 0; i < 4; ++i) {
        int r = row0 + wr * 64 + mt * 16 + (lane >> 4) * 4 + i;
        if (r < NN) {
          float x = acc[mt][nt][i] + cc;
          x = fminf(fmaxf(x, -15.f), 15.f);
          float e = __expf(2.f * x);
          s = fmaf((e - 1.f) / (e + 1.f), ww, s);
        }
      }
  }
#pragma unroll
  for (int o = 32; o > 0; o >>= 1) s += __shfl_down(s, o);
  if (lane == 0) wsumf[wave] = s;
  __syncthreads();
  if (tid == 0) atomicAdd(&ssum[p], wsumf[0] + wsumf[1] + wsumf[2] + wsumf[3]);
}

// ---------------- beta + bout + beta-scaled W^T (bf16) ----------------

__global__ void beta_kernel(const float* __restrict__ ssum, const float* __restrict__ bgc,
                            float* __restrict__ beta, float* __restrict__ bout) {
  __shared__ float sb[NP];
  if (threadIdx.x == 0) {
    float m[NP];
    float mx = -1e30f;
    for (int p = 0; p < NP; ++p) {
      m[p] = ssum[p] / (float)NN;
      mx = fmaxf(mx, m[p]);
    }
    float tot = 0.f;
    for (int p = 0; p < NP; ++p) { m[p] = expf(m[p] - mx); tot += m[p]; }
    for (int p = 0; p < NP; ++p) { sb[p] = m[p] / tot; beta[p] = sb[p]; }
  }
  __syncthreads();
  int d = threadIdx.x;  // block = 256
  float s = 0.f;
  for (int p = 0; p < NP; ++p) s = fmaf(sb[p], bgc[p * DD + d], s);
  bout[d] = s;
}

__global__ void scaleWt_kernel(const float* __restrict__ Wgc, const float* __restrict__ beta,
                               ushort* __restrict__ Wt) {
  int i = blockIdx.x * blockDim.x + threadIdx.x;  // over DD * NP * DIN
  if (i >= DD * NP * DIN) return;
  int n = i >> 10;
  int pk = i & 1023;
  int p = pk >> 8, k = pk & 255;
  Wt[i] = f2bf(beta[p] * Wgc[((size_t)p * DIN + k) * DD + n]);
}

// ---------------- gemm_main: out = [g_0|..|g_3] @ Wt^T + bout ----------------

__global__ __launch_bounds__(256) void gemm_main(
    const ushort* __restrict__ g, const ushort* __restrict__ Wt,
    const float* __restrict__ bout, float* __restrict__ out) {
  __shared__ ushort As[128 * SA];
  __shared__ ushort Bs[128 * SA];
  const int tid = threadIdx.x;
  const int row0 = blockIdx.x * 128;
  const int col0 = blockIdx.y * 128;
  const int wave = tid >> 6, lane = tid & 63;
  const int wr = wave >> 1, wc = wave & 1;
  const int srow = tid >> 2, sseg = tid & 3;
  const int fr = lane & 15, fk = (lane >> 4) * 8;
  int ar0 = row0 + srow; if (ar0 >= NN) ar0 = NN - 1;
  int ar1 = row0 + srow + 64; if (ar1 >= NN) ar1 = NN - 1;
  f32x4 acc[4][4] = {};
  for (int p = 0; p < NP; ++p) {
    const ushort* Ag = g + (size_t)p * NN * DIN;
    for (int k2 = 0; k2 < DIN; k2 += 32) {
      uint4 av0 = *(const uint4*)(Ag + (size_t)ar0 * DIN + k2 + sseg * 8);
      uint4 av1 = *(const uint4*)(Ag + (size_t)ar1 * DIN + k2 + sseg * 8);
      uint4 bv0 = *(const uint4*)(Wt + (size_t)(col0 + srow) * (NP * DIN) + p * DIN + k2 + sseg * 8);
      uint4 bv1 = *(const uint4*)(Wt + (size_t)(col0 + srow + 64) * (NP * DIN) + p * DIN + k2 + sseg * 8);
      __syncthreads();
      *(uint4*)&As[srow * SA + sseg * 8] = av0;
      *(uint4*)&As[(srow + 64) * SA + sseg * 8] = av1;
      *(uint4*)&Bs[srow * SA + sseg * 8] = bv0;
      *(uint4*)&Bs[(srow + 64) * SA + sseg * 8] = bv1;
      __syncthreads();
      bf16x8 af[4], bfv[4];
#pragma unroll
      for (int t = 0; t < 4; ++t) {
        af[t] = *(const bf16x8*)&As[(wr * 64 + t * 16 + fr) * SA + fk];
        bfv[t] = *(const bf16x8*)&Bs[(wc * 64 + t * 16 + fr) * SA + fk];
      }
#pragma unroll
      for (int mt = 0; mt < 4; ++mt)
#pragma unroll
        for (int nt = 0; nt < 4; ++nt)
          acc[mt][nt] = __builtin_amdgcn_mfma_f32_16x16x32_bf16(af[mt], bfv[nt], acc[mt][nt], 0, 0, 0);
    }
  }
#pragma unroll
  for (int nt = 0; nt < 4; ++nt) {
    int c = col0 + wc * 64 + nt * 16 + fr;
    float bb = bout[c];
#pragma unroll
    for (int mt = 0; mt < 4; ++mt)
#pragma unroll
      for (int i = 0; i < 4; ++i) {
        int r = row0 + wr * 64 + mt * 16 + (lane >> 4) * 4 + i;
        if (r < NN) out[(size_t)r * DD + c] = acc[mt][nt][i] + bb;
      }
  }
}

// ---------------- launcher ----------------

extern "C" void kernel_launch(void* const* d_in, const int* in_sizes, int n_in,
                              void* d_out, int out_size, void* d_ws, size_t ws_size,
                              hipStream_t stream) {
  const float* h = (const float*)d_in[0];
  const int* src = (const int*)d_in[1];
  const int* dst = (const int*)d_in[2];
  const float* Wgc = (const float*)d_in[3];
  const float* bgc = (const float*)d_in[4];
  const float* W1 = (const float*)d_in[5];
  const float* b1 = (const float*)d_in[6];
  const float* w2 = (const float*)d_in[7];
  float* out = (float*)d_out;

  char* base = (char*)d_ws;
  size_t off = 0;
  auto alloc = [&](size_t bytes) -> char* {
    char* ptr = base + off;
    off = (off + bytes + 255) & ~(size_t)255;
    return ptr;
  };
  int* cntD = (int*)alloc((size_t)NP * NSEG * NN * sizeof(int));
  int* cntS = (int*)alloc((size_t)NP * NSEG * NN * sizeof(int));
  float* rin = (float*)alloc((size_t)NP * NN * sizeof(float));
  float* rout = (float*)alloc((size_t)NP * NN * sizeof(float));
  int* row_ptr = (int*)alloc((size_t)NP * (NN + 1) * sizeof(int));
  int* chunkdeg = (int*)alloc((size_t)NP * NFC * sizeof(int));
  int* chunk_base = (int*)alloc((size_t)NP * NFC * sizeof(int));
  ushort* h2 = (ushort*)alloc((size_t)NN * DIN * sizeof(ushort));
  ushort* g = (ushort*)alloc((size_t)NP * NN * DIN * sizeof(ushort));
  ushort* Mt = (ushort*)alloc((size_t)NP * NH * DIN * sizeof(ushort));
  ushort* Wt = (ushort*)alloc((size_t)DD * NP * DIN * sizeof(ushort));
  float* cvec = (float*)alloc((size_t)NP * NH * sizeof(float));
  float* ssum = (float*)alloc(NP * sizeof(float));
  float* beta = (float*)alloc(NP * sizeof(float));
  float* bout = (float*)alloc(DD * sizeof(float));
  int* colbuf = (int*)cntS;  // cntS dead after scanA; scatter reuses it as col
  if (off > ws_size) return;

  hipMemsetAsync(ssum, 0, NP * sizeof(float), stream);

  hist2d_kernel<<<dim3(NFC * NSEG, NP), 256, 0, stream>>>(dst, cntD);
  hist2d_kernel<<<dim3(NFC * NSEG, NP), 256, 0, stream>>>(src, cntS);
  scanA_kernel<<<dim3(NFC, NP), 1024, 0, stream>>>(cntD, cntS, rin, rout, row_ptr, chunkdeg);
  scanB_kernel<<<1, 64, 0, stream>>>(chunkdeg, chunk_base, row_ptr);
  rpfin_kernel<<<dim3((NN + 1023) / 1024, NP), 1024, 0, stream>>>(row_ptr, chunk_base);
  cvt_h_kernel<<<(NN * DIN / 4 + 255) / 256, 256, 0, stream>>>((const float4*)h, (ushort4*)h2);
  scatter_kernel<<<dim3(NFC * NSEG, NP), 256, 0, stream>>>(src, dst, cntD, row_ptr, colbuf);
  agg_kernel<<<dim3(NN / 4, NP), 256, 0, stream>>>(h2, colbuf, row_ptr, rout, rin, g);
  wmul_kernel<<<dim3(DIN, NP), NH, 0, stream>>>(Wgc, W1, Mt);
  cvec_kernel<<<NP, NH, 0, stream>>>(bgc, W1, b1, cvec);
  gemm_sem<<<dim3((NN + 127) / 128, NP), 256, 0, stream>>>(g, Mt, cvec, w2, ssum);
  beta_kernel<<<1, 256, 0, stream>>>(ssum, bgc, beta, bout);
  scaleWt_kernel<<<(DD * NP * DIN + 255) / 256, 256, 0, stream>>>(Wgc, beta, Wt);
  gemm_main<<<dim3((NN + 127) / 128, 2), 256, 0, stream>>>(g, Wt, bout, out);
}